// Round 1
// baseline (4714.326 us; speedup 1.0000x reference)
//
#include <hip/hip_runtime.h>
#include <cstddef>

// Problem constants
#define TT   256   // timesteps
#define NN   4096  // batch
#define CC   12    // input dim
#define DD   256   // hidden dim
#define KDIM 12    // output classes
#define NB   16    // batch rows per block (NN / 256 blocks)
#define NTH  512   // threads per block (8 waves)
#define HSTR 260   // padded LDS row stride for h / wy (breaks y-phase bank conflicts)

// LDS layout: 64,256 bytes total (< 64 KB static limit)
struct SM {
  float h[NB][HSTR];        // 16,640 B  hidden state (persistent across steps)
  float part[8][4][DD];     // 32,768 B  k-split partial sums, one row-quarter at a time
  float wy[KDIM][HSTR];     // 12,480 B  dec_Wy staged (decoder only)
  float xbuf[2][NB][CC];    //  1,536 B  x_t double buffer (encoder only)
  float ybuf[NB][KDIM];     //    768 B  decoder logits for argmax
  int   idx[NB];            //     64 B  argmax feedback indices
};

__global__ __launch_bounds__(NTH)
void seq2seq_kernel(const float* __restrict__ x,
                    const float* __restrict__ enc_Wx,
                    const float* __restrict__ enc_bx,
                    const float* __restrict__ enc_Wh,
                    const float* __restrict__ dec_Wx,
                    const float* __restrict__ dec_bx,
                    const float* __restrict__ dec_Wh,
                    const float* __restrict__ dec_Wy,
                    const float* __restrict__ dec_by,
                    float* __restrict__ out)
{
  __shared__ SM sm;
  const int tid  = (int)threadIdx.x;
  const int wid  = tid >> 6;        // wave id = k-group (8 chunks of 32)
  const int lane = tid & 63;
  const int d0   = lane << 2;       // this thread owns Wh rows d0..d0+3
  const int kb   = wid << 5;        // k-chunk base
  const int n0   = (int)blockIdx.x * NB;

  // finalize mapping: each thread finalizes outs (r_local, fd) and (r_local, fd+1)
  const int frl = tid >> 7;             // row within quarter, 0..3
  const int fd  = (tid << 1) & 255;     // even d-pair base

  float4 wreg[4][8];   // 128 VGPRs: Wh[d0+i][kb + 4j .. +3]

  auto load_wh = [&](const float* __restrict__ Wh) {
    #pragma unroll
    for (int i = 0; i < 4; ++i) {
      const float4* p = (const float4*)(Wh + (size_t)(d0 + i) * DD + kb);
      #pragma unroll
      for (int j = 0; j < 8; ++j) wreg[i][j] = p[j];
    }
  };

  // MAC for one row-quarter: partial[d0..d0+3] = sum_{k in chunk} Wh[d][k] * h[r][k]
  auto mac_quarter = [&](int q) {
    #pragma unroll
    for (int rr = 0; rr < 4; ++rr) {
      const int r = (q << 2) + rr;
      const float4* hv = (const float4*)&sm.h[r][kb];   // wave-uniform -> LDS broadcast
      float a0 = 0.f, a1 = 0.f, a2 = 0.f, a3 = 0.f;
      #pragma unroll
      for (int j = 0; j < 8; ++j) {
        const float4 hh = hv[j];
        a0 = fmaf(wreg[0][j].x, hh.x, a0);
        a0 = fmaf(wreg[0][j].y, hh.y, a0);
        a0 = fmaf(wreg[0][j].z, hh.z, a0);
        a0 = fmaf(wreg[0][j].w, hh.w, a0);
        a1 = fmaf(wreg[1][j].x, hh.x, a1);
        a1 = fmaf(wreg[1][j].y, hh.y, a1);
        a1 = fmaf(wreg[1][j].z, hh.z, a1);
        a1 = fmaf(wreg[1][j].w, hh.w, a1);
        a2 = fmaf(wreg[2][j].x, hh.x, a2);
        a2 = fmaf(wreg[2][j].y, hh.y, a2);
        a2 = fmaf(wreg[2][j].z, hh.z, a2);
        a2 = fmaf(wreg[2][j].w, hh.w, a2);
        a3 = fmaf(wreg[3][j].x, hh.x, a3);
        a3 = fmaf(wreg[3][j].y, hh.y, a3);
        a3 = fmaf(wreg[3][j].z, hh.z, a3);
        a3 = fmaf(wreg[3][j].w, hh.w, a3);
      }
      *(float4*)&sm.part[wid][rr][d0] = make_float4(a0, a1, a2, a3);
    }
  };

  auto sum_parts = [&](float& s0, float& s1) {
    float2 p0 = *(const float2*)&sm.part[0][frl][fd];
    s0 = p0.x; s1 = p0.y;
    #pragma unroll
    for (int g = 1; g < 8; ++g) {
      float2 pg = *(const float2*)&sm.part[g][frl][fd];
      s0 += pg.x; s1 += pg.y;
    }
  };

  // ---------------- encoder ----------------
  load_wh(enc_Wh);

  // per-thread rows of enc_Wx for the xp term (fixed d-pair across all quarters)
  float wxp0[CC], wxp1[CC];
  #pragma unroll
  for (int c = 0; c < CC; ++c) {
    wxp0[c] = enc_Wx[(size_t)fd * CC + c];
    wxp1[c] = enc_Wx[(size_t)(fd + 1) * CC + c];
  }

  // zero h, stage x_0
  for (int i = tid; i < NB * HSTR; i += NTH) ((float*)sm.h)[i] = 0.f;
  if (tid < NB * CC) ((float*)sm.xbuf)[tid] = x[(size_t)n0 * CC + tid];
  __syncthreads();

  for (int t = 0; t < TT; ++t) {
    const int xb = t & 1;
    #pragma unroll 1
    for (int q = 0; q < 4; ++q) {
      mac_quarter(q);
      __syncthreads();
      {
        const int r = (q << 2) + frl;
        float s0, s1;
        sum_parts(s0, s1);
        float2 b = *(const float2*)&enc_bx[fd];
        s0 += b.x; s1 += b.y;
        #pragma unroll
        for (int c = 0; c < CC; ++c) {
          const float xv = sm.xbuf[xb][r][c];
          s0 = fmaf(wxp0[c], xv, s0);
          s1 = fmaf(wxp1[c], xv, s1);
        }
        s0 = fmaxf(s0, 0.f);
        s1 = fmaxf(s1, 0.f);
        *(float2*)&sm.h[r][fd] = make_float2(s0, s1);
      }
      if (q == 3 && tid < NB * CC && t + 1 < TT) {
        ((float*)sm.xbuf)[(xb ^ 1) * (NB * CC) + tid] =
            x[((size_t)(t + 1) * NN + n0) * CC + tid];
      }
      __syncthreads();
    }
  }

  // ---------------- decoder setup ----------------
  load_wh(dec_Wh);
  for (int i = tid; i < KDIM * DD; i += NTH) sm.wy[i >> 8][i & 255] = dec_Wy[i];
  if (tid < NB) sm.idx[tid] = CC - 2;   // sos0 one-hot column = 10
  __syncthreads();

  // ---------------- decoder ----------------
  for (int t = 0; t < TT; ++t) {
    #pragma unroll 1
    for (int q = 0; q < 4; ++q) {
      mac_quarter(q);
      __syncthreads();
      {
        const int r = (q << 2) + frl;
        float s0, s1;
        sum_parts(s0, s1);
        float2 b = *(const float2*)&dec_bx[fd];
        s0 += b.x; s1 += b.y;
        const int ii = sm.idx[r];   // one-hot feedback: sos @ dec_Wx.T == column gather
        s0 += dec_Wx[(size_t)fd * CC + ii];
        s1 += dec_Wx[(size_t)(fd + 1) * CC + ii];
        s0 = fmaxf(s0, 0.f);
        s1 = fmaxf(s1, 0.f);
        *(float2*)&sm.h[r][fd] = make_float2(s0, s1);
      }
      __syncthreads();
    }
    // y = h @ dec_Wy.T + dec_by ; write out ; stage logits for argmax
    if (tid < NB * KDIM) {
      const int r = tid / KDIM;
      const int kq = tid % KDIM;
      const float4* hv = (const float4*)&sm.h[r][0];
      const float4* wv = (const float4*)&sm.wy[kq][0];
      float a0 = 0.f, a1 = 0.f, a2 = 0.f, a3 = 0.f;
      #pragma unroll
      for (int j = 0; j < DD / 4; ++j) {
        const float4 hh = hv[j];
        const float4 ww = wv[j];
        a0 = fmaf(hh.x, ww.x, a0);
        a1 = fmaf(hh.y, ww.y, a1);
        a2 = fmaf(hh.z, ww.z, a2);
        a3 = fmaf(hh.w, ww.w, a3);
      }
      const float y = (a0 + a1) + (a2 + a3) + dec_by[kq];
      sm.ybuf[r][kq] = y;
      out[((size_t)t * NN + n0 + r) * KDIM + kq] = y;
    }
    __syncthreads();
    if (tid < NB) {   // argmax, first-max tie-break like np.argmax
      float best = sm.ybuf[tid][0];
      int bi = 0;
      #pragma unroll
      for (int k2 = 1; k2 < KDIM; ++k2) {
        const float v = sm.ybuf[tid][k2];
        if (v > best) { best = v; bi = k2; }
      }
      sm.idx[tid] = bi;
    }
    __syncthreads();
  }
}

extern "C" void kernel_launch(void* const* d_in, const int* in_sizes, int n_in,
                              void* d_out, int out_size, void* d_ws, size_t ws_size,
                              hipStream_t stream) {
  (void)in_sizes; (void)n_in; (void)d_ws; (void)ws_size; (void)out_size;
  const float* x      = (const float*)d_in[0];
  const float* enc_Wx = (const float*)d_in[1];
  const float* enc_bx = (const float*)d_in[2];
  const float* enc_Wh = (const float*)d_in[3];
  // d_in[4] = enc_Wy, d_in[5] = enc_by : computed-but-discarded in the reference
  const float* dec_Wx = (const float*)d_in[6];
  const float* dec_bx = (const float*)d_in[7];
  const float* dec_Wh = (const float*)d_in[8];
  const float* dec_Wy = (const float*)d_in[9];
  const float* dec_by = (const float*)d_in[10];
  float* outp = (float*)d_out;

  seq2seq_kernel<<<NN / NB, NTH, 0, stream>>>(
      x, enc_Wx, enc_bx, enc_Wh, dec_Wx, dec_bx, dec_Wh, dec_Wy, dec_by, outp);
}

// Round 2
// 1224.641 us; speedup vs baseline: 3.8496x; 3.8496x over previous
//
#include <hip/hip_runtime.h>
#include <cstdint>
#include <cstddef>

#define TT 256
#define NN 4096
#define CC 12
#define DD 256
#define KD 12
#define NB 16
#define NTH 512
#define HP 260   // dwords per packed-h row: 256 + 4 pad (16B-aligned, uniform bank windows)
#define XP 36    // dwords per packed-x row: 32 + 4 pad

typedef _Float16 half8 __attribute__((ext_vector_type(8)));
typedef float f32x4 __attribute__((ext_vector_type(4)));
#define MFMA __builtin_amdgcn_mfma_f32_16x16x32_f16

// LDS: 33,280 + 4,608 + 8,192 + 8,192 = 54,272 B
struct SM {
  unsigned hx[2][NB][HP];   // h as packed fp16 (hi | lo<<16), double-buffered
  unsigned xp[2][NB][XP];   // x_t / one-hot sos, packed fp16 pairs, cols 12..31 zero
  half8 wyhi[8][64];        // dec_Wy B-fragments, hi plane  [chunk][lane]
  half8 wylo[8][64];        // lo plane
};

__device__ __forceinline__ unsigned pack2(float v) {
  _Float16 h = (_Float16)v;
  float hf = (float)h;
  _Float16 l = (_Float16)(v - hf);
  unsigned short uh = __builtin_bit_cast(unsigned short, h);
  unsigned short ul = __builtin_bit_cast(unsigned short, l);
  return (unsigned)uh | ((unsigned)ul << 16);
}

__device__ __forceinline__ void split8(const float* w, half8& hi, half8& lo) {
  #pragma unroll
  for (int j = 0; j < 8; ++j) {
    _Float16 h = (_Float16)w[j];
    hi[j] = h;
    lo[j] = (_Float16)(w[j] - (float)h);
  }
}

// 8 packed dwords -> hi/lo half8 fragments (4 v_perm each)
__device__ __forceinline__ void unpack8(uint4 a, uint4 b, half8& hi, half8& lo) {
  unsigned h0 = __builtin_amdgcn_perm(a.y, a.x, 0x05040100u);
  unsigned h1 = __builtin_amdgcn_perm(a.w, a.z, 0x05040100u);
  unsigned h2 = __builtin_amdgcn_perm(b.y, b.x, 0x05040100u);
  unsigned h3 = __builtin_amdgcn_perm(b.w, b.z, 0x05040100u);
  unsigned l0 = __builtin_amdgcn_perm(a.y, a.x, 0x07060302u);
  unsigned l1 = __builtin_amdgcn_perm(a.w, a.z, 0x07060302u);
  unsigned l2 = __builtin_amdgcn_perm(b.y, b.x, 0x07060302u);
  unsigned l3 = __builtin_amdgcn_perm(b.w, b.z, 0x07060302u);
  hi = __builtin_bit_cast(half8, make_uint4(h0, h1, h2, h3));
  lo = __builtin_bit_cast(half8, make_uint4(l0, l1, l2, l3));
}

__global__ __launch_bounds__(NTH, 2)
void seq2seq_kernel(const float* __restrict__ x,
                    const float* __restrict__ enc_Wx,
                    const float* __restrict__ enc_bx,
                    const float* __restrict__ enc_Wh,
                    const float* __restrict__ dec_Wx,
                    const float* __restrict__ dec_bx,
                    const float* __restrict__ dec_Wh,
                    const float* __restrict__ dec_Wy,
                    const float* __restrict__ dec_by,
                    float* __restrict__ out)
{
  __shared__ SM sm;
  const int tid  = (int)threadIdx.x;
  const int wid  = tid >> 6;
  const int lane = tid & 63;
  const int l15  = lane & 15;
  const int quad = lane >> 4;
  const int n0   = (int)blockIdx.x * NB;

  half8 Whi[2][8], Wlo[2][8];   // Wh B-fragments, 128 VGPRs, persistent
  half8 Xhi[2], Xlo[2];         // Wx B-fragments (K=32 padded chunk)
  float bxr[2];

  auto loadWh = [&](const float* __restrict__ W) {
    #pragma unroll
    for (int tt = 0; tt < 2; ++tt) {
      const int n = (wid * 2 + tt) * 16 + l15;
      #pragma unroll
      for (int c = 0; c < 8; ++c) {
        float w[8];
        const float* p = W + (size_t)n * DD + c * 32 + quad * 8;
        *(float4*)&w[0] = *(const float4*)p;
        *(float4*)&w[4] = *(const float4*)(p + 4);
        split8(w, Whi[tt][c], Wlo[tt][c]);
      }
    }
  };
  auto loadWx = [&](const float* __restrict__ Wx) {
    #pragma unroll
    for (int tt = 0; tt < 2; ++tt) {
      const int n = (wid * 2 + tt) * 16 + l15;
      float w[8];
      #pragma unroll
      for (int j = 0; j < 8; ++j) {
        const int k = quad * 8 + j;
        w[j] = (k < CC) ? Wx[(size_t)n * CC + k] : 0.f;
      }
      split8(w, Xhi[tt], Xlo[tt]);
    }
  };
  auto loadBx = [&](const float* __restrict__ bx) {
    #pragma unroll
    for (int tt = 0; tt < 2; ++tt) bxr[tt] = bx[(wid * 2 + tt) * 16 + l15];
  };

  // One RNN step: read h from hx[rdbuf] + x from xp[xslot], MFMA, relu, write hx[rdbuf^1].
  auto stepA = [&](int rdbuf, int xslot, bool prefetch, const float* __restrict__ xg) {
    float pf[3];
    if (prefetch && wid == 1) {
      #pragma unroll
      for (int j = 0; j < 3; ++j) pf[j] = xg[lane + 64 * j];
    }
    f32x4 acc0 = {0.f, 0.f, 0.f, 0.f}, acc1 = {0.f, 0.f, 0.f, 0.f};
    const unsigned* hrow = &sm.hx[rdbuf][l15][0];   // A row m = lane&15
    #pragma unroll
    for (int c = 0; c < 8; ++c) {
      const uint4* p = (const uint4*)(hrow + c * 32 + quad * 8);
      const uint4 a = p[0], b = p[1];
      half8 ahi, alo;
      unpack8(a, b, ahi, alo);
      acc0 = MFMA(ahi, Whi[0][c], acc0, 0, 0, 0);
      acc1 = MFMA(ahi, Whi[1][c], acc1, 0, 0, 0);
      acc0 = MFMA(alo, Whi[0][c], acc0, 0, 0, 0);
      acc1 = MFMA(alo, Whi[1][c], acc1, 0, 0, 0);
      acc0 = MFMA(ahi, Wlo[0][c], acc0, 0, 0, 0);
      acc1 = MFMA(ahi, Wlo[1][c], acc1, 0, 0, 0);
    }
    {  // x-projection term (K=32 padded chunk; decoder one-hot is exact fp16)
      const uint4* p = (const uint4*)(&sm.xp[xslot][l15][0] + quad * 8);
      const uint4 a = p[0], b = p[1];
      half8 ahi, alo;
      unpack8(a, b, ahi, alo);
      acc0 = MFMA(ahi, Xhi[0], acc0, 0, 0, 0);
      acc1 = MFMA(ahi, Xhi[1], acc1, 0, 0, 0);
      acc0 = MFMA(alo, Xhi[0], acc0, 0, 0, 0);
      acc1 = MFMA(alo, Xhi[1], acc1, 0, 0, 0);
      acc0 = MFMA(ahi, Xlo[0], acc0, 0, 0, 0);
      acc1 = MFMA(ahi, Xlo[1], acc1, 0, 0, 0);
    }
    // epilogue: bias + relu + pack fp16x2, write new h (C/D: m=quad*4+reg, n=tile*16+l15)
    #pragma unroll
    for (int r = 0; r < 4; ++r) {
      const int m = quad * 4 + r;
      const float v0 = fmaxf(acc0[r] + bxr[0], 0.f);
      const float v1 = fmaxf(acc1[r] + bxr[1], 0.f);
      sm.hx[rdbuf ^ 1][m][(wid * 2 + 0) * 16 + l15] = pack2(v0);
      sm.hx[rdbuf ^ 1][m][(wid * 2 + 1) * 16 + l15] = pack2(v1);
    }
    if (prefetch && wid == 1) {
      #pragma unroll
      for (int j = 0; j < 3; ++j) {
        const int i = lane + 64 * j;
        sm.xp[xslot ^ 1][i / CC][i % CC] = pack2(pf[j]);
      }
    }
  };

  // ---------------- init ----------------
  {
    unsigned* hz = &sm.hx[0][0][0];
    for (int i = tid; i < NB * HP; i += NTH) hz[i] = 0u;
    unsigned* xz = &sm.xp[0][0][0];
    for (int i = tid; i < 2 * NB * XP; i += NTH) xz[i] = 0u;
  }
  loadWh(enc_Wh);
  loadWx(enc_Wx);
  loadBx(enc_bx);
  __syncthreads();
  if (tid < NB * CC) {  // stage x_0
    const float v = x[(size_t)n0 * CC + tid];
    sm.xp[0][tid / CC][tid % CC] = pack2(v);
  }
  __syncthreads();

  // ---------------- encoder: 1 barrier/step ----------------
  for (int t = 0; t < TT; ++t) {
    stepA(t & 1, t & 1, t + 1 < TT, x + ((size_t)(t + 1) * NN + n0) * CC);
    __syncthreads();
  }
  // encoder final h now in hx[0]

  // ---------------- decoder setup ----------------
  loadWh(dec_Wh);
  loadWx(dec_Wx);
  loadBx(dec_bx);
  const float byv = (l15 < KD) ? dec_by[l15] : 0.f;
  {  // stage dec_Wy fragments (B[k][n]: n=lane&15, k=chunk*32+quad*8+j)
    const int c = tid >> 6, ln = tid & 63, q2 = ln >> 4, n = ln & 15;
    float w[8];
    if (n < KD) {
      const float* p = dec_Wy + (size_t)n * DD + c * 32 + q2 * 8;
      *(float4*)&w[0] = *(const float4*)p;
      *(float4*)&w[4] = *(const float4*)(p + 4);
    } else {
      #pragma unroll
      for (int j = 0; j < 8; ++j) w[j] = 0.f;
    }
    half8 hi, lo;
    split8(w, hi, lo);
    sm.wyhi[c][ln] = hi;
    sm.wylo[c][ln] = lo;
  }
  if (wid == 0) {  // sos one-hot: column CC-2 = 10
    const int m2 = lane >> 2, cb = (lane & 3) * 8;
    #pragma unroll
    for (int j = 0; j < 8; ++j) sm.xp[0][m2][cb + j] = (cb + j == 10) ? 0x3C00u : 0u;
  }
  __syncthreads();

  // ---------------- decoder: 2 barriers/step ----------------
  for (int t = 0; t < TT; ++t) {
    stepA(t & 1, 0, false, x);
    __syncthreads();
    if (wid == 0) {
      // y = h_new @ Wy^T + by  (single-wave MFMA, N-tile padded 12->16)
      f32x4 yacc = {0.f, 0.f, 0.f, 0.f};
      const unsigned* hrow = &sm.hx[(t & 1) ^ 1][l15][0];
      #pragma unroll
      for (int c = 0; c < 8; ++c) {
        const uint4* p = (const uint4*)(hrow + c * 32 + quad * 8);
        const uint4 a = p[0], b = p[1];
        half8 ahi, alo;
        unpack8(a, b, ahi, alo);
        const half8 bh = sm.wyhi[c][lane];
        const half8 bl = sm.wylo[c][lane];
        yacc = MFMA(ahi, bh, yacc, 0, 0, 0);
        yacc = MFMA(alo, bh, yacc, 0, 0, 0);
        yacc = MFMA(ahi, bl, yacc, 0, 0, 0);
      }
      float vr[4];
      int idxr[4];
      #pragma unroll
      for (int r = 0; r < 4; ++r) {
        const float yv = yacc[r] + byv;
        const int m = quad * 4 + r;
        if (l15 < KD) out[((size_t)t * NN + n0 + m) * KD + l15] = yv;
        vr[r] = (l15 < KD) ? yv : -1e30f;
        idxr[r] = l15;
      }
      // argmax across the 16-lane n-groups, first-max tie-break (np semantics)
      #pragma unroll
      for (int d = 1; d < 16; d <<= 1) {
        #pragma unroll
        for (int r = 0; r < 4; ++r) {
          const float ov = __shfl_xor(vr[r], d);
          const int oi = __shfl_xor(idxr[r], d);
          const bool take = (ov > vr[r]) || (ov == vr[r] && oi < idxr[r]);
          vr[r] = take ? ov : vr[r];
          idxr[r] = take ? oi : idxr[r];
        }
      }
      // redistribute idx[m] to one-hot writers: writer lane covers row m2=lane>>2
      const int src = (lane >> 4) << 4;           // any lane in quad group m2>>2
      const int g0 = __shfl(idxr[0], src);
      const int g1 = __shfl(idxr[1], src);
      const int g2 = __shfl(idxr[2], src);
      const int g3 = __shfl(idxr[3], src);
      const int rr = (lane >> 2) & 3;
      const int myidx = rr == 0 ? g0 : rr == 1 ? g1 : rr == 2 ? g2 : g3;
      const int m2 = lane >> 2, cb = (lane & 3) * 8;
      #pragma unroll
      for (int j = 0; j < 8; ++j)
        sm.xp[0][m2][cb + j] = (cb + j == myidx) ? 0x3C00u : 0u;
    }
    __syncthreads();
  }
}

extern "C" void kernel_launch(void* const* d_in, const int* in_sizes, int n_in,
                              void* d_out, int out_size, void* d_ws, size_t ws_size,
                              hipStream_t stream) {
  (void)in_sizes; (void)n_in; (void)d_ws; (void)ws_size; (void)out_size;
  const float* x      = (const float*)d_in[0];
  const float* enc_Wx = (const float*)d_in[1];
  const float* enc_bx = (const float*)d_in[2];
  const float* enc_Wh = (const float*)d_in[3];
  // d_in[4] enc_Wy, d_in[5] enc_by: computed-but-discarded in the reference
  const float* dec_Wx = (const float*)d_in[6];
  const float* dec_bx = (const float*)d_in[7];
  const float* dec_Wh = (const float*)d_in[8];
  const float* dec_Wy = (const float*)d_in[9];
  const float* dec_by = (const float*)d_in[10];
  float* outp = (float*)d_out;

  seq2seq_kernel<<<NN / NB, NTH, 0, stream>>>(
      x, enc_Wx, enc_bx, enc_Wh, dec_Wx, dec_bx, dec_Wh, dec_Wy, dec_by, outp);
}